// Round 4
// baseline (198.213 us; speedup 1.0000x reference)
//
#include <hip/hip_runtime.h>

#define B_ 128
#define NPG 512
#define EPG 2048
#define NREL 114
#define XS 20   // s_x row stride in floats (80B, 16B-aligned rows)
#define WS 20   // s_wq/s_wk row stride in floats

// monotone float->uint key (total order matching float compare, no NaNs here)
__device__ __forceinline__ unsigned fkey(float f){
  unsigned u = __float_as_uint(f);
  return (u & 0x80000000u) ? ~u : (u | 0x80000000u);
}
__device__ __forceinline__ float fdec(unsigned k){
  return (k & 0x80000000u) ? __uint_as_float(k & 0x7FFFFFFFu) : __uint_as_float(~k);
}
__device__ __forceinline__ float dot4(float4 a, float4 b){
  return a.x*b.x + a.y*b.y + a.z*b.z + a.w*b.w;
}

// One block per graph. Whole network LDS-resident, edges counting-sorted by
// relation type once (improves W-gather + wq/wk locality), 1 launch total.
__global__ __launch_bounds__(1024) void k_fused(
    const float* __restrict__ emb, const float* __restrict__ gnn_w,
    const float* __restrict__ gnn_q, const float* __restrict__ gnn_k,
    const float* __restrict__ gnn_b, const float* __restrict__ pool_w,
    const float* __restrict__ w1, const float* __restrict__ b1,
    const float* __restrict__ w2, const float* __restrict__ b2,
    const float* __restrict__ w3, const float* __restrict__ b3,
    const int* __restrict__ xattr, const int* __restrict__ src,
    const int* __restrict__ dst, const int* __restrict__ et,
    float* __restrict__ out)
{
  __shared__ float s_x[NPG*XS];          // 40960 B
  __shared__ float s_num[NPG*17];        // 34816 B (stride 17: scalar atomics)
  __shared__ float s_wq[NREL*WS];        // 9120 B
  __shared__ float s_wk[NREL*WS];        // 9120 B
  __shared__ float s_logit[EPG];         // 8192 B
  __shared__ unsigned s_mkey[NPG];
  __shared__ float s_den[NPG];
  __shared__ int s_mask[NPG];
  __shared__ unsigned s_keys[NPG];
  __shared__ unsigned short s_src[EPG], s_dst[EPG], s_et[EPG];  // sorted by type
  __shared__ int s_hist[NREL+1];
  __shared__ float s_sum[16];
  __shared__ unsigned s_max16[16];
  __shared__ int s_w[8];
  __shared__ float s_feats[96];
  __shared__ float s_h1[16], s_h2[4];

  const int b = blockIdx.x, tid = threadIdx.x;
  const int lane = tid & 63, wv = tid >> 6;
  const size_t gbase = (size_t)b*EPG;
  const int nb = b*NPG;

  // ---- init: emb gather (float4) + counting-sort edges by type
  if (tid < NPG){
    int a = xattr[nb + tid];
    const float4* e4 = (const float4*)(emb + a*16);
    #pragma unroll
    for (int c=0;c<4;c++) *(float4*)&s_x[tid*XS + 4*c] = e4[c];
    s_mask[tid] = 1;
  }
  for (int i=tid; i<NREL; i+=1024) s_hist[i]=0;
  __syncthreads();
  for (int e=tid; e<EPG; e+=1024) atomicAdd(&s_hist[et[gbase+e]], 1);
  __syncthreads();
  if (tid==0){
    int acc=0;
    for (int r=0;r<NREL;r++){ int c=s_hist[r]; s_hist[r]=acc; acc+=c; }
    s_hist[NREL]=acc;
  }
  __syncthreads();
  for (int e=tid; e<EPG; e+=1024){
    int r = et[gbase+e];
    int p = atomicAdd(&s_hist[r], 1);
    s_src[p] = (unsigned short)(src[gbase+e] - nb);
    s_dst[p] = (unsigned short)(dst[gbase+e] - nb);
    s_et[p]  = (unsigned short)r;
  }

  const int cnts[3] = {512, 410, 328};   // static alive counts
  const int kks[3]  = {410, 328, 0};     // ceil(0.8*512), ceil(0.8*410)

  for (int l=0; l<3; ++l){
    const float* Wl = gnn_w + (size_t)l*NREL*256;
    // ---- A: Wq/Wk precompute (logit is bilinear) + zero accumulators
    {
      const float* qv = gnn_q + l*16;
      const float* kv = gnn_k + l*16;
      float4 q0=((const float4*)qv)[0], q1=((const float4*)qv)[1],
             q2=((const float4*)qv)[2], q3=((const float4*)qv)[3];
      float4 k0=((const float4*)kv)[0], k1=((const float4*)kv)[1],
             k2=((const float4*)kv)[2], k3=((const float4*)kv)[3];
      for (int i = tid; i < NREL*16; i += 1024){
        const float4* wr = (const float4*)(Wl + (size_t)i*16);
        float4 a0=wr[0], a1=wr[1], a2=wr[2], a3=wr[3];
        float aq = dot4(a0,q0)+dot4(a1,q1)+dot4(a2,q2)+dot4(a3,q3);
        float ak = dot4(a0,k0)+dot4(a1,k1)+dot4(a2,k2)+dot4(a3,k3);
        s_wq[(i>>4)*WS + (i&15)] = aq;
        s_wk[(i>>4)*WS + (i&15)] = ak;
      }
      for (int i = tid; i < NPG*17; i += 1024) s_num[i] = 0.f;
      if (tid < NPG){ s_mkey[tid]=0u; s_den[tid]=0.f; }
    }
    __syncthreads();
    // ---- P1: edge logits + segment max; b128 LDS reads, wq/wk mostly broadcast
    for (int e = tid; e < EPG; e += 1024){
      int s = s_src[e], t = s_dst[e];
      if (!s_mask[s] || !s_mask[t]) continue;
      int r = s_et[e];
      const float4* xt4 = (const float4*)&s_x[t*XS];
      const float4* xs4 = (const float4*)&s_x[s*XS];
      const float4* q4  = (const float4*)&s_wq[r*WS];
      const float4* k4  = (const float4*)&s_wk[r*WS];
      float acc = dot4(xt4[0],q4[0]) + dot4(xt4[1],q4[1])
                + dot4(xt4[2],q4[2]) + dot4(xt4[3],q4[3])
                + dot4(xs4[0],k4[0]) + dot4(xs4[1],k4[1])
                + dot4(xs4[2],k4[2]) + dot4(xs4[3],k4[3]);
      float lg = acc > 0.f ? acc : 0.2f*acc;   // leaky_relu 0.2
      s_logit[e] = lg;
      atomicMax(&s_mkey[t], fkey(lg));
    }
    __syncthreads();
    // ---- P2: h_s = x_s*W_r, weighted aggregation. 4 lanes/edge, sorted edges
    //      => a wave's 16 edges share few types => W row loads coalesce/broadcast
    {
      const int og = tid & 3;
      for (int e = (tid>>2); e < EPG; e += 256){
        int s = s_src[e], t = s_dst[e];
        if (!s_mask[s] || !s_mask[t]) continue;
        float m = fdec(s_mkey[t]);
        float ex = expf(s_logit[e] - m);
        const float4* xs4 = (const float4*)&s_x[s*XS];
        float4 x0=xs4[0], x1=xs4[1], x2=xs4[2], x3=xs4[3];
        const float4* wr = (const float4*)(Wl + (size_t)s_et[e]*256) + og;
        float4 h; h.x=0.f; h.y=0.f; h.z=0.f; h.w=0.f;
        float xv[16] = {x0.x,x0.y,x0.z,x0.w, x1.x,x1.y,x1.z,x1.w,
                        x2.x,x2.y,x2.z,x2.w, x3.x,x3.y,x3.z,x3.w};
        #pragma unroll
        for (int d=0; d<16; d++){
          float4 w = wr[d*4];
          h.x += xv[d]*w.x; h.y += xv[d]*w.y; h.z += xv[d]*w.z; h.w += xv[d]*w.w;
        }
        int base = t*17 + og*4;
        atomicAdd(&s_num[base+0], ex*h.x);
        atomicAdd(&s_num[base+1], ex*h.y);
        atomicAdd(&s_num[base+2], ex*h.z);
        atomicAdd(&s_num[base+3], ex*h.w);
        if (og==0) atomicAdd(&s_den[t], ex);
      }
    }
    __syncthreads();
    if (tid < 16){ s_sum[tid]=0.f; s_max16[tid]=0u; }
    __syncthreads();
    // ---- N: normalize + relu + mean/max pool
    float v[16]; float sc = 0.f; unsigned mykey = 0u; int alive = 0;
    if (tid < NPG){
      alive = s_mask[tid];
      if (alive){
        float dn = s_den[tid];
        float inv = dn>0.f ? 1.f/dn : 1.f;   // ref: where(den>0, den, 1)
        #pragma unroll
        for (int o=0;o<16;o++){
          float z = s_num[tid*17+o]*inv + gnn_b[l*16+o];
          v[o] = z>0.f?z:0.f;
        }
      } else {
        #pragma unroll
        for (int o=0;o<16;o++) v[o]=0.f;
      }
      #pragma unroll
      for (int o=0;o<16;o++){
        float sv=v[o], mv=v[o];
        #pragma unroll
        for (int off=32; off; off>>=1){
          sv += __shfl_xor(sv, off);
          mv = fmaxf(mv, __shfl_xor(mv, off));
        }
        if (lane==0){ atomicAdd(&s_sum[o], sv); atomicMax(&s_max16[o], __float_as_uint(mv)); }
      }
    }
    __syncthreads();
    if (tid < 16){
      s_feats[l*32 + tid]      = s_sum[tid]/(float)cnts[l];
      s_feats[l*32 + 16 + tid] = __uint_as_float(s_max16[tid]);
    }
    if (l < 2){
      const int kk = kks[l];
      if (tid < NPG){
        float ss=0.f, dot=0.f;
        #pragma unroll
        for (int o=0;o<16;o++){ float p = pool_w[l*16+o]; ss += p*p; dot += v[o]*p; }
        sc = tanhf(dot / sqrtf(ss));
        mykey = alive ? fkey(sc) : 0u;   // dead -> 0; alive keys always > 0
        s_keys[tid] = mykey;
      }
      __syncthreads();
      // register-resident wave-redundant bitwise search for the kk-th key
      int ties=0, lrank=0; bool eq=false; unsigned cur=0u;
      if (tid < NPG){
        unsigned kreg[8];
        #pragma unroll
        for (int j=0;j<8;j++) kreg[j] = s_keys[lane + j*64];
        for (int bit=31; bit>=0; --bit){
          unsigned cand = cur | (1u<<bit);
          int c=0;
          #pragma unroll
          for (int j=0;j<8;j++) c += (kreg[j] >= cand) ? 1 : 0;
          #pragma unroll
          for (int off=32; off; off>>=1) c += __shfl_xor(c, off);
          if (c >= kk) cur = cand;
        }
        int cgt=0;
        #pragma unroll
        for (int j=0;j<8;j++) cgt += (kreg[j] > cur) ? 1 : 0;
        #pragma unroll
        for (int off=32; off; off>>=1) cgt += __shfl_xor(cgt, off);
        ties = kk - cgt;
        // rank among equals by node index (jax top_k lowest-index tie-break)
        eq = alive && (mykey == cur);
        unsigned long long bal = __ballot(eq);
        lrank = __popcll(bal & ((1ull<<lane)-1ull));
        if (lane==0) s_w[wv] = __popcll(bal);
      }
      __syncthreads();
      if (tid < NPG){
        int pre=0;
        #pragma unroll
        for (int w=0; w<8; ++w) if (w<wv) pre += s_w[w];
        int rank = pre + lrank;
        bool keep = alive && ((mykey > cur) || (eq && rank < ties));
        float mult = keep ? sc : 0.f;
        #pragma unroll
        for (int c=0;c<4;c++){
          float4 t4;
          t4.x=v[4*c+0]*mult; t4.y=v[4*c+1]*mult; t4.z=v[4*c+2]*mult; t4.w=v[4*c+3]*mult;
          *(float4*)&s_x[tid*XS + 4*c] = t4;
        }
        s_mask[tid] = keep ? 1 : 0;
      }
      __syncthreads();
    } else {
      __syncthreads();   // make s_feats visible for the MLP
    }
  }

  // ---- MLP head (per graph, feats never leave LDS)
  if (tid < 16){
    float a = b1[tid];
    for (int i=0;i<96;i++) a += s_feats[i]*w1[i*16+tid];
    s_h1[tid] = a>0.f?a:0.f;
  }
  __syncthreads();
  if (tid < 4){
    float a = b2[tid];
    #pragma unroll
    for (int i=0;i<16;i++) a += s_h1[i]*w2[i*4+tid];
    s_h2[tid] = a>0.f?a:0.f;
  }
  __syncthreads();
  if (tid == 0){
    float z = b3[0];
    #pragma unroll
    for (int i=0;i<4;i++) z += s_h2[i]*w3[i];
    out[b] = 1.f/(1.f+expf(-z));
  }
}

extern "C" void kernel_launch(void* const* d_in, const int* in_sizes, int n_in,
                              void* d_out, int out_size, void* d_ws, size_t ws_size,
                              hipStream_t stream) {
  const float* emb    = (const float*)d_in[0];
  const float* gnn_w  = (const float*)d_in[1];
  const float* gnn_q  = (const float*)d_in[2];
  const float* gnn_k  = (const float*)d_in[3];
  const float* gnn_b  = (const float*)d_in[4];
  const float* pool_w = (const float*)d_in[5];
  const float* w1 = (const float*)d_in[6];
  const float* b1 = (const float*)d_in[7];
  const float* w2 = (const float*)d_in[8];
  const float* b2 = (const float*)d_in[9];
  const float* w3 = (const float*)d_in[10];
  const float* b3 = (const float*)d_in[11];
  const int* xattr = (const int*)d_in[12];
  const int* eidx  = (const int*)d_in[13];
  const int* etype = (const int*)d_in[14];
  const int* src = eidx;
  const int* dst = eidx + (size_t)B_*EPG;

  k_fused<<<B_, 1024, 0, stream>>>(emb, gnn_w, gnn_q, gnn_k, gnn_b, pool_w,
                                   w1, b1, w2, b2, w3, b3,
                                   xattr, src, dst, etype, (float*)d_out);
}